// Round 16
// baseline (138.703 us; speedup 1.0000x reference)
//
#include <hip/hip_runtime.h>

typedef unsigned short u16;
typedef unsigned int   u32;
typedef __bf16 bf16x4 __attribute__((ext_vector_type(4)));
typedef __bf16 bf16x8 __attribute__((ext_vector_type(8)));
typedef float  f32x4  __attribute__((ext_vector_type(4)));

__device__ __forceinline__ u16 f2bf(float f) {
  u32 u = __float_as_uint(f);
  u32 r = (u + 0x7fffu + ((u >> 16) & 1u)) >> 16;   // RNE
  return (u16)r;
}

__device__ __forceinline__ float fexp2(float x) {
  return __builtin_amdgcn_exp2f(x);   // bare v_exp_f32
}

typedef const __attribute__((address_space(1))) u32* gp1;
typedef __attribute__((address_space(3))) u32* lp3;
__device__ __forceinline__ void gload16(const void* g, void* l) {
  __builtin_amdgcn_global_load_lds((gp1)g, (lp3)l, 16, 0, 0);
}

__device__ __forceinline__ f32x4 mfma16(bf16x8 a, bf16x8 b, f32x4 c) {
  return __builtin_amdgcn_mfma_f32_16x16x32_bf16(a, b, c, 0, 0, 0);
}

__device__ __forceinline__ int swz8(int r) { return (r ^ (r >> 3)) & 7; }

// ---------------- fused cast fp32 -> bf16 for x, w_qkv, w_out (one launch) -------
__global__ __launch_bounds__(256) void cast_all(const float* __restrict__ x,
                                                const float* __restrict__ wqkv,
                                                const float* __restrict__ wo,
                                                uint4* __restrict__ dst) {
  int i = blockIdx.x * 256 + threadIdx.x;      // 16B chunk index
  if (i >= 1081344) return;
  const float* s;
  int j;
  if (i < 786432)       { s = x;    j = i; }
  else if (i < 1007616) { s = wqkv; j = i - 786432; }
  else                  { s = wo;   j = i - 1007616; }
  const float4* s4 = (const float4*)s;
  float4 a = s4[2 * j], b = s4[2 * j + 1];
  uint4 o;
  o.x = (u32)f2bf(a.x) | ((u32)f2bf(a.y) << 16);
  o.y = (u32)f2bf(a.z) | ((u32)f2bf(a.w) << 16);
  o.z = (u32)f2bf(b.x) | ((u32)f2bf(b.y) << 16);
  o.w = (u32)f2bf(b.z) | ((u32)f2bf(b.w) << 16);
  dst[i] = o;
}

// Virtual-row packed tile: RxK (K=32 bf16) stored as [R/2 vrows][128B];
// chunk-within-vrow XOR'd with swz8(vr). Fragment reads are 2-way-bank (free).
// Staging: linear LDS dest chunk c -> inverse-swizzled global source.

// ---------------- QKV GEMM: C(8192x2304) = Xb(8192x768) * Wqkv^T ----------------
// BK=32, 3-buffer, counted vmcnt (T4), raw barriers. XCD panel-chunked grid.
// Q scaled by 0.125*log2(e); V stored TRANSPOSED [b,h,d,n]
__global__ __launch_bounds__(256, 3) void gemm_qkv(
    const u16* __restrict__ A, const u16* __restrict__ Bm,
    const float* __restrict__ bias,
    u16* __restrict__ Q, u16* __restrict__ K, u16* __restrict__ V) {
  __shared__ u16 As[3][64 * 64];   // 128x32 tile, virtual-packed
  __shared__ u16 Bs[3][64 * 64];
  const int tid = threadIdx.x, w = tid >> 6, l = tid & 63;
  const int lr = l & 15, lg = l >> 4;
  int id = blockIdx.x;
  int bi = (id & 7) * 144 + (id >> 3);     // 8 XCDs x 144 (8 m-panels x 18 n)
  const int m0 = (bi / 18) * 128, n0 = (bi % 18) * 128;
  const int wr = (w >> 1) * 64, wc = (w & 1) * 64;
  f32x4 acc[4][4] = {};

#define QSTAGE(ab, bb, kt)                                                     \
  do {                                                                         \
    const u16* Ab = A + m0 * 768 + (kt);                                       \
    const u16* Bb = Bm + n0 * 768 + (kt);                                      \
    _Pragma("unroll") for (int i = 0; i < 2; ++i) {                            \
      int c = i * 256 + tid;                                                   \
      int vr = c >> 3;                                                         \
      int chl = (c & 7) ^ swz8(vr);                                            \
      int r = vr * 2 + (chl >> 2), col = (chl & 3) * 8;                        \
      gload16(Ab + r * 768 + col, (char*)(ab) + c * 16);                       \
      gload16(Bb + r * 768 + col, (char*)(bb) + c * 16);                       \
    }                                                                          \
  } while (0)

  u16 *aC = As[0], *aN = As[1], *aF = As[2];
  u16 *bC = Bs[0], *bN = Bs[1], *bF = Bs[2];
  QSTAGE(aC, bC, 0);
  QSTAGE(aN, bN, 32);

  for (int t = 0; t < 24; ++t) {
    if (t == 23) asm volatile("s_waitcnt vmcnt(0)" ::: "memory");
    else         asm volatile("s_waitcnt vmcnt(4)" ::: "memory");
    __builtin_amdgcn_s_barrier();
    __builtin_amdgcn_sched_barrier(0);
    if (t < 22) QSTAGE(aF, bF, (t + 2) * 32);

    bf16x8 fa[4], fb[4];
#pragma unroll
    for (int m = 0; m < 4; ++m) {
      int row = wr + m * 16 + lr;
      int vr = row >> 1;
      int chs = (((row & 1) << 2) | lg) ^ swz8(vr);
      fa[m] = *(const bf16x8*)((char*)aC + vr * 128 + (chs << 4));
    }
#pragma unroll
    for (int n = 0; n < 4; ++n) {
      int row = wc + n * 16 + lr;
      int vr = row >> 1;
      int chs = (((row & 1) << 2) | lg) ^ swz8(vr);
      fb[n] = *(const bf16x8*)((char*)bC + vr * 128 + (chs << 4));
    }
    __builtin_amdgcn_s_setprio(1);
#pragma unroll
    for (int m = 0; m < 4; ++m)
#pragma unroll
      for (int n = 0; n < 4; ++n) acc[m][n] = mfma16(fa[m], fb[n], acc[m][n]);
    __builtin_amdgcn_s_setprio(0);

    u16* ta = aC; aC = aN; aN = aF; aF = ta;
    u16* tb = bC; bC = bN; bN = bF; bF = tb;
  }

#pragma unroll
  for (int n = 0; n < 4; ++n) {
    int f = n0 + wc + n * 16 + lr;
    float bv = bias[f];
    int three = f / 768;
    int hd = f - three * 768;
    int h = hd >> 6, dd = hd & 63;
    if (three == 2) {
      // V^T: row = (b*12+h)*64+dd, 4 consecutive tokens per 8B store
#pragma unroll
      for (int m = 0; m < 4; ++m) {
        int row0 = m0 + wr + m * 16 + lg * 4;
        int b2 = row0 >> 11, ns = row0 & 2047;
        ushort4 pk;
        pk.x = f2bf(acc[m][n][0] + bv);
        pk.y = f2bf(acc[m][n][1] + bv);
        pk.z = f2bf(acc[m][n][2] + bv);
        pk.w = f2bf(acc[m][n][3] + bv);
        *(ushort4*)&V[((size_t)(b2 * 12 + h) * 64 + dd) * 2048 + ns] = pk;
      }
    } else {
      u16* dst = (three == 0) ? Q : K;
      float sc = (three == 0) ? 0.125f * 1.44269504f : 1.0f;  // fold log2(e) into Q
#pragma unroll
      for (int m = 0; m < 4; ++m) {
        int row0 = m0 + wr + m * 16 + lg * 4;
#pragma unroll
        for (int j = 0; j < 4; ++j) {
          int row = row0 + j;
          int b2 = row >> 11, ns = row & 2047;
          float val = (acc[m][n][j] + bv) * sc;
          dst[(((b2 * 12 + h) * 2048 + ns) << 6) + dd] = f2bf(val);
        }
      }
    }
  }
}

// ---------------- flash attention v15 (frozen, 63 µs): 3-buffer, counted vmcnt ---
__global__ __launch_bounds__(256, 3) void attn_kernel(
    const u16* __restrict__ Q, const u16* __restrict__ K,
    const u16* __restrict__ Vt, u16* __restrict__ O) {
  __shared__ u16 Ks[3][64 * 64];   // [kv][d] rows 128B, chunk^swz8(row)
  __shared__ u16 Vs[3][64 * 64];   // [d][kv] rows 128B, chunk^swz8(row)
  const int tid = threadIdx.x, w = tid >> 6, l = tid & 63;
  const int lr = l & 15, lg = l >> 4;
  int d0i = blockIdx.x;
  int bi = (d0i & 7) * 96 + (d0i >> 3);          // XCD swizzle: 6 heads per XCD
  int qt = bi & 15, h = (bi >> 4) % 12, b = bi / 192;
  const u16* Qp = Q + ((size_t)(b * 12 + h) * 2048 + qt * 128) * 64;
  const u16* Kp = K + (size_t)(b * 12 + h) * 2048 * 64;
  const u16* Vp = Vt + (size_t)(b * 12 + h) * 64 * 2048;   // [d][n]
  u16* Op = O + (size_t)(b * 2048 + qt * 128) * 768 + h * 64;

  bf16x8 aq[2][2];
#pragma unroll
  for (int mt = 0; mt < 2; ++mt)
#pragma unroll
    for (int ks = 0; ks < 2; ++ks)
      aq[mt][ks] = *(const bf16x8*)&Qp[(w * 32 + mt * 16 + lr) * 64 + ks * 32 + lg * 8];

  bf16x8 vone;
#pragma unroll
  for (int i = 0; i < 8; ++i) vone[i] = (__bf16)1.0f;

  f32x4 aO[2][4] = {};
  f32x4 sacc[2] = {};   // rowsum of P via ones-MFMA; reg j <-> q = lg*4+j

#define STAGEP(kb, vb, kt)                                                     \
  do {                                                                         \
    const u16* Kt = Kp + (kt) * 4096;                                          \
    const u16* Vg = Vp + (kt) * 64;                                            \
    _Pragma("unroll") for (int i = 0; i < 2; ++i) {                            \
      int c = i * 256 + tid;                                                   \
      int r = c >> 3, q = c & 7;                                               \
      int qs = (q ^ swz8(r)) << 3;                                             \
      gload16(Kt + r * 64 + qs, (char*)(kb) + c * 16);                         \
      gload16(Vg + r * 2048 + qs, (char*)(vb) + c * 16);                       \
    }                                                                          \
  } while (0)

  u16 *kc = Ks[0], *kn = Ks[1], *kf = Ks[2];
  u16 *vc = Vs[0], *vn = Vs[1], *vf = Vs[2];

  STAGEP(kc, vc, 0);
  STAGEP(kn, vn, 1);   // 8 outstanding

  for (int kt = 0; kt < 32; ++kt) {
    if (kt == 31) asm volatile("s_waitcnt vmcnt(0)" ::: "memory");
    else          asm volatile("s_waitcnt vmcnt(4)" ::: "memory");
    __builtin_amdgcn_s_barrier();
    __builtin_amdgcn_sched_barrier(0);
    if (kt < 30) STAGEP(kf, vf, kt + 2);   // depth-2 prefetch (WAR-safe)

    // ---- S^T = K·Q^T from kc ----
    f32x4 S[2][4] = {};
    __builtin_amdgcn_s_setprio(1);
#pragma unroll
    for (int nt = 0; nt < 4; ++nt) {
      int row = nt * 16 + lr;
      int sw = swz8(row);
#pragma unroll
      for (int ks = 0; ks < 2; ++ks) {
        bf16x8 a = *(const bf16x8*)((char*)kc + row * 128 +
                                    (((ks * 4 + lg) ^ sw) << 4));
        S[0][nt] = mfma16(a, aq[0][ks], S[0][nt]);
        S[1][nt] = mfma16(a, aq[1][ks], S[1][nt]);
      }
    }
    __builtin_amdgcn_s_setprio(0);

    // ---- softmax: P = 2^S unnormalized (no max tracking); P in registers ----
    bf16x8 ap[2][2];
#pragma unroll
    for (int mt = 0; mt < 2; ++mt) {
      f32x4 pe[4];
#pragma unroll
      for (int nt = 0; nt < 4; ++nt)
#pragma unroll
        for (int j = 0; j < 4; ++j) pe[nt][j] = fexp2(S[mt][nt][j]);
#pragma unroll
      for (int ks = 0; ks < 2; ++ks) {
        bf16x8 f;
#pragma unroll
        for (int j = 0; j < 4; ++j) {
          f[j]     = (__bf16)pe[2 * ks][j];
          f[4 + j] = (__bf16)pe[2 * ks + 1][j];
        }
        ap[mt][ks] = f;
      }
    }

    // ---- O += P·V ; rowsum via ones-MFMA ----
    __builtin_amdgcn_s_setprio(1);
#pragma unroll
    for (int ks = 0; ks < 2; ++ks) {
      sacc[0] = mfma16(ap[0][ks], vone, sacc[0]);
      sacc[1] = mfma16(ap[1][ks], vone, sacc[1]);
#pragma unroll
      for (int dt = 0; dt < 4; ++dt) {
        int row = dt * 16 + lr;
        int sw = swz8(row);
        char* vrow = (char*)vc + row * 128 + (lg & 1) * 8;
        bf16x4 lo = *(const bf16x4*)(vrow + (((ks * 4 + (lg >> 1)) ^ sw) << 4));
        bf16x4 hi = *(const bf16x4*)(vrow + (((ks * 4 + 2 + (lg >> 1)) ^ sw) << 4));
        bf16x8 bv = __builtin_shufflevector(lo, hi, 0, 1, 2, 3, 4, 5, 6, 7);
        aO[0][dt] = mfma16(ap[0][ks], bv, aO[0][dt]);
        aO[1][dt] = mfma16(ap[1][ks], bv, aO[1][dt]);
      }
    }
    __builtin_amdgcn_s_setprio(0);

    u16* tk = kc; kc = kn; kn = kf; kf = tk;
    u16* tv = vc; vc = vn; vn = vf; vf = tv;
  }

#pragma unroll
  for (int mt = 0; mt < 2; ++mt) {
    f32x4 rinv;
#pragma unroll
    for (int j = 0; j < 4; ++j) rinv[j] = 1.0f / sacc[mt][j];
#pragma unroll
    for (int dt = 0; dt < 4; ++dt)
#pragma unroll
      for (int j = 0; j < 4; ++j) {
        int row = w * 32 + mt * 16 + lg * 4 + j;
        Op[(size_t)row * 768 + dt * 16 + lr] = f2bf(aO[mt][dt][j] * rinv[j]);
      }
  }
}

// ---------------- out GEMM: C(8192x768) = Ob(8192x768) * Wout^T + b, fp32 out ----
// BK=32, BN=64 (grid 768 = 3/CU), 3-buffer, counted vmcnt, XCD panel-chunked.
__global__ __launch_bounds__(256, 3) void gemm_out(
    const u16* __restrict__ A, const u16* __restrict__ Bm,
    const float* __restrict__ bias, float* __restrict__ C) {
  __shared__ u16 As[3][64 * 64];   // 128x32 tile, virtual-packed
  __shared__ u16 Bs[3][32 * 64];   // 64x32 tile, virtual-packed
  const int tid = threadIdx.x, w = tid >> 6, l = tid & 63;
  const int lr = l & 15, lg = l >> 4;
  int id = blockIdx.x;
  int bi = (id & 7) * 96 + (id >> 3);     // 8 XCDs x 96 (8 m-panels x 12 n)
  const int m0 = (bi / 12) * 128, n0 = (bi % 12) * 64;
  const int wr = (w >> 1) * 64, wc = (w & 1) * 32;
  f32x4 acc[4][2] = {};

#define OSTAGE(ab, bb, kt)                                                     \
  do {                                                                         \
    const u16* Ab = A + m0 * 768 + (kt);                                       \
    const u16* Bb = Bm + n0 * 768 + (kt);                                      \
    _Pragma("unroll") for (int i = 0; i < 2; ++i) {                            \
      int c = i * 256 + tid;                                                   \
      int vr = c >> 3;                                                         \
      int chl = (c & 7) ^ swz8(vr);                                            \
      int r = vr * 2 + (chl >> 2), col = (chl & 3) * 8;                        \
      gload16(Ab + r * 768 + col, (char*)(ab) + c * 16);                       \
    }                                                                          \
    {                                                                          \
      int c = tid;                                                             \
      int vr = c >> 3;                                                         \
      int chl = (c & 7) ^ swz8(vr);                                            \
      int r = vr * 2 + (chl >> 2), col = (chl & 3) * 8;                        \
      gload16(Bb + r * 768 + col, (char*)(bb) + c * 16);                       \
    }                                                                          \
  } while (0)

  u16 *aC = As[0], *aN = As[1], *aF = As[2];
  u16 *bC = Bs[0], *bN = Bs[1], *bF = Bs[2];
  OSTAGE(aC, bC, 0);
  OSTAGE(aN, bN, 32);

  for (int t = 0; t < 24; ++t) {
    if (t == 23) asm volatile("s_waitcnt vmcnt(0)" ::: "memory");
    else         asm volatile("s_waitcnt vmcnt(3)" ::: "memory");
    __builtin_amdgcn_s_barrier();
    __builtin_amdgcn_sched_barrier(0);
    if (t < 22) OSTAGE(aF, bF, (t + 2) * 32);

    bf16x8 fa[4], fb[2];
#pragma unroll
    for (int m = 0; m < 4; ++m) {
      int row = wr + m * 16 + lr;
      int vr = row >> 1;
      int chs = (((row & 1) << 2) | lg) ^ swz8(vr);
      fa[m] = *(const bf16x8*)((char*)aC + vr * 128 + (chs << 4));
    }
#pragma unroll
    for (int n = 0; n < 2; ++n) {
      int row = wc + n * 16 + lr;
      int vr = row >> 1;
      int chs = (((row & 1) << 2) | lg) ^ swz8(vr);
      fb[n] = *(const bf16x8*)((char*)bC + vr * 128 + (chs << 4));
    }
    __builtin_amdgcn_s_setprio(1);
#pragma unroll
    for (int m = 0; m < 4; ++m)
#pragma unroll
      for (int n = 0; n < 2; ++n) acc[m][n] = mfma16(fa[m], fb[n], acc[m][n]);
    __builtin_amdgcn_s_setprio(0);

    u16* ta = aC; aC = aN; aN = aF; aF = ta;
    u16* tb = bC; bC = bN; bN = bF; bF = tb;
  }

#pragma unroll
  for (int n = 0; n < 2; ++n) {
    int f = n0 + wc + n * 16 + lr;
    float bv = bias[f];
#pragma unroll
    for (int m = 0; m < 4; ++m) {
      int row0 = m0 + wr + m * 16 + lg * 4;
#pragma unroll
      for (int j = 0; j < 4; ++j) {
        int row = row0 + j;
        C[(size_t)row * 768 + f] = acc[m][n][j] + bv;
      }
    }
  }
}

extern "C" void kernel_launch(void* const* d_in, const int* in_sizes, int n_in,
                              void* d_out, int out_size, void* d_ws, size_t ws_size,
                              hipStream_t stream) {
  const float* x     = (const float*)d_in[0];
  const float* w_qkv = (const float*)d_in[1];
  const float* b_qkv = (const float*)d_in[2];
  const float* w_out = (const float*)d_in[3];
  const float* b_out = (const float*)d_in[4];

  char* ws = (char*)d_ws;
  u16* xb    = (u16*)(ws + 0);
  u16* wqkvb = (u16*)(ws + 12582912);
  u16* wob   = (u16*)(ws + 16121856);
  u16* qb    = (u16*)(ws + 17301504);
  u16* kb    = (u16*)(ws + 29884416);
  u16* vb    = (u16*)(ws + 42467328);   // V^T [b,h,d,n]
  u16* ob    = (u16*)(ws + 55050240);

  cast_all<<<4224, 256, 0, stream>>>(x, w_qkv, w_out, (uint4*)ws);

  gemm_qkv<<<1152, 256, 0, stream>>>(xb, wqkvb, b_qkv, qb, kb, vb);
  attn_kernel<<<768, 256, 0, stream>>>(qb, kb, vb, ob);
  gemm_out<<<768, 256, 0, stream>>>(ob, wob, b_out, (float*)d_out);
}

// Round 17
// 132.267 us; speedup vs baseline: 1.0487x; 1.0487x over previous
//
#include <hip/hip_runtime.h>

typedef unsigned short u16;
typedef unsigned int   u32;
typedef __bf16 bf16x4 __attribute__((ext_vector_type(4)));
typedef __bf16 bf16x8 __attribute__((ext_vector_type(8)));
typedef float  f32x4  __attribute__((ext_vector_type(4)));

__device__ __forceinline__ u16 f2bf(float f) {
  u32 u = __float_as_uint(f);
  u32 r = (u + 0x7fffu + ((u >> 16) & 1u)) >> 16;   // RNE
  return (u16)r;
}

__device__ __forceinline__ float fexp2(float x) {
  return __builtin_amdgcn_exp2f(x);   // bare v_exp_f32
}

typedef const __attribute__((address_space(1))) u32* gp1;
typedef __attribute__((address_space(3))) u32* lp3;
__device__ __forceinline__ void gload16(const void* g, void* l) {
  __builtin_amdgcn_global_load_lds((gp1)g, (lp3)l, 16, 0, 0);
}

__device__ __forceinline__ f32x4 mfma16(bf16x8 a, bf16x8 b, f32x4 c) {
  return __builtin_amdgcn_mfma_f32_16x16x32_bf16(a, b, c, 0, 0, 0);
}

__device__ __forceinline__ int swz8(int r) { return (r ^ (r >> 3)) & 7; }

// ---------------- fused cast fp32 -> bf16 for x, w_qkv, w_out (one launch) -------
__global__ __launch_bounds__(256) void cast_all(const float* __restrict__ x,
                                                const float* __restrict__ wqkv,
                                                const float* __restrict__ wo,
                                                uint4* __restrict__ dst) {
  int i = blockIdx.x * 256 + threadIdx.x;      // 16B chunk index
  if (i >= 1081344) return;
  const float* s;
  int j;
  if (i < 786432)       { s = x;    j = i; }
  else if (i < 1007616) { s = wqkv; j = i - 786432; }
  else                  { s = wo;   j = i - 1007616; }
  const float4* s4 = (const float4*)s;
  float4 a = s4[2 * j], b = s4[2 * j + 1];
  uint4 o;
  o.x = (u32)f2bf(a.x) | ((u32)f2bf(a.y) << 16);
  o.y = (u32)f2bf(a.z) | ((u32)f2bf(a.w) << 16);
  o.z = (u32)f2bf(b.x) | ((u32)f2bf(b.y) << 16);
  o.w = (u32)f2bf(b.z) | ((u32)f2bf(b.w) << 16);
  dst[i] = o;
}

// ---------------- QKV GEMM: C(8192x2304) = Xb(8192x768) * Wqkv^T ----------------
// BK=64, swizzled LDS, double-buffered (1 barrier/iter), XCD panel-chunked grid.
__global__ __launch_bounds__(256) void gemm_qkv(
    const u16* __restrict__ A, const u16* __restrict__ Bm,
    const float* __restrict__ bias,
    u16* __restrict__ Q, u16* __restrict__ K, u16* __restrict__ V) {
  __shared__ u16 As[2][128 * 64];
  __shared__ u16 Bs[2][128 * 64];
  const int tid = threadIdx.x, w = tid >> 6, l = tid & 63;
  const int lr = l & 15, lg = l >> 4;
  int id = blockIdx.x;
  int bi = (id & 7) * 144 + (id >> 3);
  const int m0 = (bi / 18) * 128, n0 = (bi % 18) * 128;
  const int wr = (w >> 1) * 64, wc = (w & 1) * 64;
  f32x4 acc[4][4] = {};

#define GSTAGE(buf, kt)                                                        \
  do {                                                                         \
    const u16* Ab = A + m0 * 768 + (kt);                                       \
    const u16* Bb = Bm + n0 * 768 + (kt);                                      \
    _Pragma("unroll") for (int i = 0; i < 4; ++i) {                            \
      int c = i * 256 + tid;                                                   \
      int r = c >> 3, q = c & 7;                                               \
      int qs = (q ^ swz8(r)) << 3;                                             \
      gload16(Ab + r * 768 + qs, (char*)As[buf] + c * 16);                     \
      gload16(Bb + r * 768 + qs, (char*)Bs[buf] + c * 16);                     \
    }                                                                          \
  } while (0)

  GSTAGE(0, 0);
  __syncthreads();

  for (int t = 0; t < 12; ++t) {
    const int buf = t & 1;
    if (t < 11) GSTAGE(buf ^ 1, (t + 1) * 64);   // prefetch next tile
    bf16x8 af[4][2], bfr[4][2];
#pragma unroll
    for (int m = 0; m < 4; ++m) {
      int row = wr + m * 16 + lr;
      int sw = swz8(row);
#pragma unroll
      for (int ks = 0; ks < 2; ++ks)
        af[m][ks] = *(const bf16x8*)((char*)As[buf] + row * 128 +
                                     (((ks * 4 + lg) ^ sw) << 4));
    }
#pragma unroll
    for (int n = 0; n < 4; ++n) {
      int row = wc + n * 16 + lr;
      int sw = swz8(row);
#pragma unroll
      for (int ks = 0; ks < 2; ++ks)
        bfr[n][ks] = *(const bf16x8*)((char*)Bs[buf] + row * 128 +
                                      (((ks * 4 + lg) ^ sw) << 4));
    }
    __builtin_amdgcn_s_setprio(1);
#pragma unroll
    for (int ks = 0; ks < 2; ++ks)
#pragma unroll
      for (int m = 0; m < 4; ++m)
#pragma unroll
        for (int n = 0; n < 4; ++n)
          acc[m][n] = mfma16(af[m][ks], bfr[n][ks], acc[m][n]);
    __builtin_amdgcn_s_setprio(0);
    __syncthreads();
  }

#pragma unroll
  for (int n = 0; n < 4; ++n) {
    int f = n0 + wc + n * 16 + lr;
    float bv = bias[f];
    int three = f / 768;
    int hd = f - three * 768;
    int h = hd >> 6, dd = hd & 63;
    if (three == 2) {
#pragma unroll
      for (int m = 0; m < 4; ++m) {
        int row0 = m0 + wr + m * 16 + lg * 4;
        int b2 = row0 >> 11, ns = row0 & 2047;
        ushort4 pk;
        pk.x = f2bf(acc[m][n][0] + bv);
        pk.y = f2bf(acc[m][n][1] + bv);
        pk.z = f2bf(acc[m][n][2] + bv);
        pk.w = f2bf(acc[m][n][3] + bv);
        *(ushort4*)&V[((size_t)(b2 * 12 + h) * 64 + dd) * 2048 + ns] = pk;
      }
    } else {
      u16* dst = (three == 0) ? Q : K;
      float sc = (three == 0) ? 0.125f * 1.44269504f : 1.0f;  // fold log2(e) into Q
#pragma unroll
      for (int m = 0; m < 4; ++m) {
        int row0 = m0 + wr + m * 16 + lg * 4;
#pragma unroll
        for (int j = 0; j < 4; ++j) {
          int row = row0 + j;
          int b2 = row >> 11, ns = row & 2047;
          float val = (acc[m][n][j] + bv) * sc;
          dst[(((b2 * 12 + h) * 2048 + ns) << 6) + dd] = f2bf(val);
        }
      }
    }
  }
}

// ---------------- flash attention v15: 3-buffer, counted vmcnt (T4), raw barrier --
// 128 q-rows/block (32/wave), KVBLK=64, depth-2 prefetch: STAGE(t+2) after barrier,
// wait vmcnt(4) keeps tile t+1's loads in flight across the barrier.
__global__ __launch_bounds__(256, 3) void attn_kernel(
    const u16* __restrict__ Q, const u16* __restrict__ K,
    const u16* __restrict__ Vt, u16* __restrict__ O) {
  __shared__ u16 Ks[3][64 * 64];   // [kv][d] rows 128B, chunk^swz8(row)
  __shared__ u16 Vs[3][64 * 64];   // [d][kv] rows 128B, chunk^swz8(row)
  const int tid = threadIdx.x, w = tid >> 6, l = tid & 63;
  const int lr = l & 15, lg = l >> 4;
  int d0i = blockIdx.x;
  int bi = (d0i & 7) * 96 + (d0i >> 3);          // XCD swizzle: 6 heads per XCD
  int qt = bi & 15, h = (bi >> 4) % 12, b = bi / 192;
  const u16* Qp = Q + ((size_t)(b * 12 + h) * 2048 + qt * 128) * 64;
  const u16* Kp = K + (size_t)(b * 12 + h) * 2048 * 64;
  const u16* Vp = Vt + (size_t)(b * 12 + h) * 64 * 2048;   // [d][n]
  u16* Op = O + (size_t)(b * 2048 + qt * 128) * 768 + h * 64;

  bf16x8 aq[2][2];
#pragma unroll
  for (int mt = 0; mt < 2; ++mt)
#pragma unroll
    for (int ks = 0; ks < 2; ++ks)
      aq[mt][ks] = *(const bf16x8*)&Qp[(w * 32 + mt * 16 + lr) * 64 + ks * 32 + lg * 8];

  bf16x8 vone;
#pragma unroll
  for (int i = 0; i < 8; ++i) vone[i] = (__bf16)1.0f;

  f32x4 aO[2][4] = {};
  f32x4 sacc[2] = {};   // rowsum of P via ones-MFMA; reg j <-> q = lg*4+j

#define STAGEP(kb, vb, kt)                                                     \
  do {                                                                         \
    const u16* Kt = Kp + (kt) * 4096;                                          \
    const u16* Vg = Vp + (kt) * 64;                                            \
    _Pragma("unroll") for (int i = 0; i < 2; ++i) {                            \
      int c = i * 256 + tid;                                                   \
      int r = c >> 3, q = c & 7;                                               \
      int qs = (q ^ swz8(r)) << 3;                                             \
      gload16(Kt + r * 64 + qs, (char*)(kb) + c * 16);                         \
      gload16(Vg + r * 2048 + qs, (char*)(vb) + c * 16);                       \
    }                                                                          \
  } while (0)

  u16 *kc = Ks[0], *kn = Ks[1], *kf = Ks[2];
  u16 *vc = Vs[0], *vn = Vs[1], *vf = Vs[2];

  STAGEP(kc, vc, 0);
  STAGEP(kn, vn, 1);   // 8 outstanding

  for (int kt = 0; kt < 32; ++kt) {
    if (kt == 31) asm volatile("s_waitcnt vmcnt(0)" ::: "memory");
    else          asm volatile("s_waitcnt vmcnt(4)" ::: "memory");
    __builtin_amdgcn_s_barrier();
    __builtin_amdgcn_sched_barrier(0);
    if (kt < 30) STAGEP(kf, vf, kt + 2);   // depth-2 prefetch (WAR-safe)

    // ---- S^T = K·Q^T from kc ----
    f32x4 S[2][4] = {};
    __builtin_amdgcn_s_setprio(1);
#pragma unroll
    for (int nt = 0; nt < 4; ++nt) {
      int row = nt * 16 + lr;
      int sw = swz8(row);
#pragma unroll
      for (int ks = 0; ks < 2; ++ks) {
        bf16x8 a = *(const bf16x8*)((char*)kc + row * 128 +
                                    (((ks * 4 + lg) ^ sw) << 4));
        S[0][nt] = mfma16(a, aq[0][ks], S[0][nt]);
        S[1][nt] = mfma16(a, aq[1][ks], S[1][nt]);
      }
    }
    __builtin_amdgcn_s_setprio(0);

    // ---- softmax: P = 2^S unnormalized (no max tracking); P in registers ----
    bf16x8 ap[2][2];
#pragma unroll
    for (int mt = 0; mt < 2; ++mt) {
      f32x4 pe[4];
#pragma unroll
      for (int nt = 0; nt < 4; ++nt)
#pragma unroll
        for (int j = 0; j < 4; ++j) pe[nt][j] = fexp2(S[mt][nt][j]);
#pragma unroll
      for (int ks = 0; ks < 2; ++ks) {
        bf16x8 f;
#pragma unroll
        for (int j = 0; j < 4; ++j) {
          f[j]     = (__bf16)pe[2 * ks][j];
          f[4 + j] = (__bf16)pe[2 * ks + 1][j];
        }
        ap[mt][ks] = f;
      }
    }

    // ---- O += P·V ; rowsum via ones-MFMA ----
    __builtin_amdgcn_s_setprio(1);
#pragma unroll
    for (int ks = 0; ks < 2; ++ks) {
      sacc[0] = mfma16(ap[0][ks], vone, sacc[0]);
      sacc[1] = mfma16(ap[1][ks], vone, sacc[1]);
#pragma unroll
      for (int dt = 0; dt < 4; ++dt) {
        int row = dt * 16 + lr;
        int sw = swz8(row);
        char* vrow = (char*)vc + row * 128 + (lg & 1) * 8;
        bf16x4 lo = *(const bf16x4*)(vrow + (((ks * 4 + (lg >> 1)) ^ sw) << 4));
        bf16x4 hi = *(const bf16x4*)(vrow + (((ks * 4 + 2 + (lg >> 1)) ^ sw) << 4));
        bf16x8 bv = __builtin_shufflevector(lo, hi, 0, 1, 2, 3, 4, 5, 6, 7);
        aO[0][dt] = mfma16(ap[0][ks], bv, aO[0][dt]);
        aO[1][dt] = mfma16(ap[1][ks], bv, aO[1][dt]);
      }
    }
    __builtin_amdgcn_s_setprio(0);

    u16* tk = kc; kc = kn; kn = kf; kf = tk;
    u16* tv = vc; vc = vn; vn = vf; vf = tv;
  }

#pragma unroll
  for (int mt = 0; mt < 2; ++mt) {
    f32x4 rinv;
#pragma unroll
    for (int j = 0; j < 4; ++j) rinv[j] = 1.0f / sacc[mt][j];
#pragma unroll
    for (int dt = 0; dt < 4; ++dt)
#pragma unroll
      for (int j = 0; j < 4; ++j) {
        int row = w * 32 + mt * 16 + lg * 4 + j;
        Op[(size_t)row * 768 + dt * 16 + lr] = f2bf(aO[mt][dt][j] * rinv[j]);
      }
  }
}

// ---------------- out GEMM: C(8192x768) = Ob(8192x768) * Wout^T + b, fp32 out ----
__global__ __launch_bounds__(256) void gemm_out(
    const u16* __restrict__ A, const u16* __restrict__ Bm,
    const float* __restrict__ bias, float* __restrict__ C) {
  __shared__ u16 As[2][128 * 64];
  __shared__ u16 Bs[2][128 * 64];
  const int tid = threadIdx.x, w = tid >> 6, l = tid & 63;
  const int lr = l & 15, lg = l >> 4;
  int id = blockIdx.x;
  int bi = (id & 7) * 48 + (id >> 3);
  const int m0 = (bi / 6) * 128, n0 = (bi % 6) * 128;
  const int wr = (w >> 1) * 64, wc = (w & 1) * 64;
  f32x4 acc[4][4] = {};

  GSTAGE(0, 0);
  __syncthreads();

  for (int t = 0; t < 12; ++t) {
    const int buf = t & 1;
    if (t < 11) GSTAGE(buf ^ 1, (t + 1) * 64);
    bf16x8 af[4][2], bfr[4][2];
#pragma unroll
    for (int m = 0; m < 4; ++m) {
      int row = wr + m * 16 + lr;
      int sw = swz8(row);
#pragma unroll
      for (int ks = 0; ks < 2; ++ks)
        af[m][ks] = *(const bf16x8*)((char*)As[buf] + row * 128 +
                                     (((ks * 4 + lg) ^ sw) << 4));
    }
#pragma unroll
    for (int n = 0; n < 4; ++n) {
      int row = wc + n * 16 + lr;
      int sw = swz8(row);
#pragma unroll
      for (int ks = 0; ks < 2; ++ks)
        bfr[n][ks] = *(const bf16x8*)((char*)Bs[buf] + row * 128 +
                                      (((ks * 4 + lg) ^ sw) << 4));
    }
    __builtin_amdgcn_s_setprio(1);
#pragma unroll
    for (int ks = 0; ks < 2; ++ks)
#pragma unroll
      for (int m = 0; m < 4; ++m)
#pragma unroll
        for (int n = 0; n < 4; ++n)
          acc[m][n] = mfma16(af[m][ks], bfr[n][ks], acc[m][n]);
    __builtin_amdgcn_s_setprio(0);
    __syncthreads();
  }

#pragma unroll
  for (int n = 0; n < 4; ++n) {
    int f = n0 + wc + n * 16 + lr;
    float bv = bias[f];
#pragma unroll
    for (int m = 0; m < 4; ++m) {
      int row0 = m0 + wr + m * 16 + lg * 4;
#pragma unroll
      for (int j = 0; j < 4; ++j) {
        int row = row0 + j;
        C[(size_t)row * 768 + f] = acc[m][n][j] + bv;
      }
    }
  }
}

extern "C" void kernel_launch(void* const* d_in, const int* in_sizes, int n_in,
                              void* d_out, int out_size, void* d_ws, size_t ws_size,
                              hipStream_t stream) {
  const float* x     = (const float*)d_in[0];
  const float* w_qkv = (const float*)d_in[1];
  const float* b_qkv = (const float*)d_in[2];
  const float* w_out = (const float*)d_in[3];
  const float* b_out = (const float*)d_in[4];

  char* ws = (char*)d_ws;
  u16* xb    = (u16*)(ws + 0);
  u16* wqkvb = (u16*)(ws + 12582912);
  u16* wob   = (u16*)(ws + 16121856);
  u16* qb    = (u16*)(ws + 17301504);
  u16* kb    = (u16*)(ws + 29884416);
  u16* vb    = (u16*)(ws + 42467328);   // V^T [b,h,d,n]
  u16* ob    = (u16*)(ws + 55050240);

  cast_all<<<4224, 256, 0, stream>>>(x, w_qkv, w_out, (uint4*)ws);

  gemm_qkv<<<1152, 256, 0, stream>>>(xb, wqkvb, b_qkv, qb, kb, vb);
  attn_kernel<<<768, 256, 0, stream>>>(qb, kb, vb, ob);
  gemm_out<<<384, 256, 0, stream>>>(ob, wob, b_out, (float*)d_out);
}